// Round 15
// baseline (80.834 us; speedup 1.0000x reference)
//
#include <hip/hip_runtime.h>
#include <stdint.h>

#define T_TRIALS 1000
#define B_SIZE   8192
#define P_SIZE   1024
#define ER_DECAY 0.999f
#define ER_L2D   (-1.4434228e-3f)   // log2(0.999)
#define LOG2E_F 1.4426950408889634f
#define LN2_F   0.69314718055994531f

typedef float f32x4_t __attribute__((ext_vector_type(4)));

__device__ __forceinline__ float sp_(float x){ return __logf(1.0f + __expf(x)); }   // softplus
__device__ __forceinline__ float sg_(float x){ return 1.0f / (1.0f + __expf(-x)); } // sigmoid
__device__ __forceinline__ float clampf(float x, float lo, float hi){ return fminf(fmaxf(x, lo), hi); }

// ===========================================================================
// fused5: 1024-thread blocks = 64 k-slots x 16 b, CHUNK=16, dynamic LDS 81.5KB.
// Chunks 0..61 full (16 steps), chunk 62 = tail 8 steps. Maps stored for
// chunks 0..59 only; emit slots 61/62 replay chunk 60(/61) state from LDS
// packed words. Slot 63 idle.
// ===========================================================================
#define F5_CHUNK  16
#define F5_NMST   60           // stored maps
#define F5_LDS_BYTES 81536

__global__ __launch_bounds__(1024, 8)
void castro_fused5(const float* __restrict__ params,
                   const float* __restrict__ rewards,
                   const int*   __restrict__ choices,
                   const int*   __restrict__ pids,
                   float4*      __restrict__ out4)
{
    extern __shared__ char lds_raw[];
    float4*   smap0  = (float4*)lds_raw;               // [60*16]
    float4*   smap1  = smap0 + 960;
    float4*   smap2  = smap1 + 960;
    float4*   smap3  = smap2 + 960;
    float4*   smap4  = smap3 + 960;
    uint32_t* smeta  = (uint32_t*)(smap4 + 960);       // [60*16]
    float*    pshare = (float*)(smeta + 960);          // [16*10]
    uint32_t* tailw  = (uint32_t*)(pshare + 160);      // [4*16]

    const int tid = threadIdx.x;
    const int k   = tid >> 4;          // 0..63
    const int bi  = tid & 15;
    const int b   = blockIdx.x * 16 + bi;
    const int t0  = k * F5_CHUNK;
    const int pid = pids[b];

    const float p3  = clampf(params[ 3 * P_SIZE + pid], -5.0f, 5.0f);
    const float p4  = clampf(params[ 4 * P_SIZE + pid], -5.0f, 5.0f);
    const float p10 = clampf(params[10 * P_SIZE + pid], -5.0f, 5.0f);
    const float alpha_er = clampf(sg_(p3), 0.01f, 0.99f);
    const float decay    = clampf(sg_(p4), 0.01f, 0.99f);
    const float gam      = sp_(p10);
    const float gp1      = 1.0f + gam;

    if (tid < 16) {
        const float q0_ = clampf(params[ 0 * P_SIZE + pid], -5.0f, 5.0f);
        const float q1_ = clampf(params[ 1 * P_SIZE + pid], -5.0f, 5.0f);
        const float q2_ = clampf(params[ 2 * P_SIZE + pid], -5.0f, 5.0f);
        const float q5_ = clampf(params[ 5 * P_SIZE + pid], -5.0f, 5.0f);
        const float q6_ = clampf(params[ 6 * P_SIZE + pid], -5.0f, 5.0f);
        const float q7_ = clampf(params[ 7 * P_SIZE + pid], -5.0f, 5.0f);
        const float q8_ = clampf(params[ 8 * P_SIZE + pid], -5.0f, 5.0f);
        const float q11 = clampf(params[11 * P_SIZE + pid], -5.0f, 5.0f);
        const float q12 = clampf(params[12 * P_SIZE + pid], -5.0f, 5.0f);
        const float beta_r = clampf(sp_(q0_), 0.01f, 20.0f);
        const float lapse  = clampf(sg_(q1_), 0.01f, 0.99f);
        const float prior  = clampf(sp_(q2_), 0.01f, 0.99f);
        const float temp   = clampf(sp_(q11) + 1e-6f, 1e-6f, 100.0f);
        float* ps = pshare + tid * 10;
        ps[0] = (beta_r / temp) * LOG2E_F;   // bt2
        ps[1] = 1.0f - lapse;                // ol
        ps[2] = 0.25f * lapse;               // la4
        ps[3] = prior;
        ps[4] = sp_(q7_);                    // perv
        ps[5] = q8_;                         // sw
        ps[6] = q5_;                         // ab1
        ps[7] = q6_;                         // ab2
        ps[8] = sp_(q12);                    // beta_p
        ps[9] = 0.0f;
    }

    const int*   cp = choices + (size_t)t0 * B_SIZE + b;
    const float* rp = rewards + (size_t)t0 * B_SIZE + b;

    uint32_t wr[2] = {0u, 0u};

    // ---------------- phase 1 ----------------
    if (k < F5_NMST) {
        float er = alpha_er * exp2f((float)t0 * ER_L2D);

        float m00=1.f,m01=0.f,m02=0.f,m03=0.f;
        float m10=0.f,m11=1.f,m12=0.f,m13=0.f;
        float m20=0.f,m21=0.f,m22=1.f,m23=0.f;
        float m30=0.f,m31=0.f,m32=0.f,m33=1.f;
        float b0=0.f,b1=0.f,b2=0.f,b3=0.f;
        int   c1=0,c2=0,c3=0;
        int   run=0, last=-1;

        int cbuf[8]; float rbuf[8];
        #pragma unroll
        for (int i = 0; i < 8; ++i) {
            cbuf[i] = cp[(size_t)i * B_SIZE];
            rbuf[i] = rp[(size_t)i * B_SIZE];
        }

        #pragma unroll
        for (int g = 0; g < 2; ++g) {
            int cc[8]; float rr[8];
            #pragma unroll
            for (int i = 0; i < 8; ++i) { cc[i]=cbuf[i]; rr[i]=rbuf[i]; }
            if (g < 1) {
                #pragma unroll
                for (int i = 0; i < 8; ++i) {
                    cbuf[i] = cp[(size_t)(8 + i) * B_SIZE];
                    rbuf[i] = rp[(size_t)(8 + i) * B_SIZE];
                }
            }
            uint32_t gw = 0;
            #pragma unroll
            for (int i = 0; i < 8; ++i) {
                const int   c = cc[i];
                const float r = rr[i];
                gw |= ((uint32_t)c | (r > 0.5f ? 4u : 0u)) << (4*i);

                er *= ER_DECAY;
                const float target = fmaf(r, gp1, -gam);
                const bool e0=(c==0), e1=(c==1), e2=(c==2), e3=(c==3);

                m00=e0?0.f:m00; m01=e0?0.f:m01; m02=e0?0.f:m02; m03=e0?0.f:m03; b0=e0?target:b0;
                m10=e1?0.f:m10; m11=e1?0.f:m11; m12=e1?0.f:m12; m13=e1?0.f:m13; b1=e1?target:b1;
                m20=e2?0.f:m20; m21=e2?0.f:m21; m22=e2?0.f:m22; m23=e2?0.f:m23; b2=e2?target:b2;
                m30=e3?0.f:m30; m31=e3?0.f:m31; m32=e3?0.f:m32; m33=e3?0.f:m33; b3=e3?target:b3;

                const float s0=(m00+m10)+(m20+m30);
                const float s1=(m01+m11)+(m21+m31);
                const float s2=(m02+m12)+(m22+m32);
                const float s3=(m03+m13)+(m23+m33);
                const float sb=(b0+b1)+(b2+b3);
                const float a  = decay * (1.0f - er);
                const float e4 = decay * er * 0.25f;

                m00=fmaf(e4,s0,a*m00); m01=fmaf(e4,s1,a*m01); m02=fmaf(e4,s2,a*m02); m03=fmaf(e4,s3,a*m03);
                m10=fmaf(e4,s0,a*m10); m11=fmaf(e4,s1,a*m11); m12=fmaf(e4,s2,a*m12); m13=fmaf(e4,s3,a*m13);
                m20=fmaf(e4,s0,a*m20); m21=fmaf(e4,s1,a*m21); m22=fmaf(e4,s2,a*m22); m23=fmaf(e4,s3,a*m23);
                m30=fmaf(e4,s0,a*m30); m31=fmaf(e4,s1,a*m31); m32=fmaf(e4,s2,a*m32); m33=fmaf(e4,s3,a*m33);
                b0=fmaf(e4,sb,a*b0); b1=fmaf(e4,sb,a*b1); b2=fmaf(e4,sb,a*b2); b3=fmaf(e4,sb,a*b3);

                c1 += e1; c2 += e2; c3 += e3;
                run = (c == last) ? run + 1 : 1;
                last = c;
            }
            wr[g] = gw;
        }

        const int si = k * 16 + bi;
        smap0[si] = make_float4(m00,m01,m02,m03);
        smap1[si] = make_float4(m10,m11,m12,m13);
        smap2[si] = make_float4(m20,m21,m22,m23);
        smap3[si] = make_float4(m30,m31,m32,m33);
        smap4[si] = make_float4(b0,b1,b2,b3);
        smeta[si] = (uint32_t)c1 | ((uint32_t)c2<<6) | ((uint32_t)c3<<12)
                  | ((uint32_t)last<<18) | ((uint32_t)run<<20);
    } else if (k < 62) {
        // chunks 60,61: pack only; words also to LDS for replay slots
        #pragma unroll
        for (int g = 0; g < 2; ++g) {
            uint32_t gw = 0;
            #pragma unroll
            for (int i = 0; i < 8; ++i) {
                const int   c = cp[(size_t)(g*8 + i) * B_SIZE];
                const float r = rp[(size_t)(g*8 + i) * B_SIZE];
                gw |= ((uint32_t)c | (r > 0.5f ? 4u : 0u)) << (4*i);
            }
            wr[g] = gw;
            tailw[((k - 60)*2 + g) * 16 + bi] = gw;
        }
    } else if (k == 62) {
        // tail chunk [992,1000): 1 word
        uint32_t gw = 0;
        #pragma unroll
        for (int i = 0; i < 8; ++i) {
            const int   c = cp[(size_t)i * B_SIZE];
            const float r = rp[(size_t)i * B_SIZE];
            gw |= ((uint32_t)c | (r > 0.5f ? 4u : 0u)) << (4*i);
        }
        wr[0] = gw;
    }
    // k == 63: idle

    __syncthreads();

    // ---------------- phase 2: serial scan (threads 0..15) ----------------
    // checkpoint entering chunk k2 overlays consumed rows smap0/1[k2-1]
    if (tid < 16) {
        const float prior = pshare[tid*10 + 3];
        float q0=prior, q1=prior, q2=prior, q3=prior;
        int n0=0,n1=0,n2=0,n3=0;
        int g_run=0, g_last=-1;

        for (int k2 = 0; k2 <= F5_NMST; ++k2) {
            if (k2 > 0) {
                const int tsls = g_run - 1;
                const int si = (k2-1)*16 + tid;
                smap0[si] = make_float4(q0,q1,q2,q3);
                smap1[si] = make_float4(0.0f,
                                        __int_as_float(n0 | (n1<<16)),
                                        __int_as_float(n2 | (n3<<16)),
                                        __int_as_float((tsls & 0xFFFF) | (g_last<<16)));
            }
            if (k2 < F5_NMST) {
                const int si = k2*16 + tid;
                const float4 r0 = smap0[si];
                const float4 r1 = smap1[si];
                const float4 r2 = smap2[si];
                const float4 r3 = smap3[si];
                const float4 r4 = smap4[si];
                const uint32_t m = smeta[si];
                const float nq0 = fmaf(r0.w,q3, fmaf(r0.z,q2, fmaf(r0.y,q1, fmaf(r0.x,q0, r4.x))));
                const float nq1 = fmaf(r1.w,q3, fmaf(r1.z,q2, fmaf(r1.y,q1, fmaf(r1.x,q0, r4.y))));
                const float nq2 = fmaf(r2.w,q3, fmaf(r2.z,q2, fmaf(r2.y,q1, fmaf(r2.x,q0, r4.z))));
                const float nq3 = fmaf(r3.w,q3, fmaf(r3.z,q2, fmaf(r3.y,q1, fmaf(r3.x,q0, r4.w))));
                q0=nq0; q1=nq1; q2=nq2; q3=nq3;

                const int cc1 = (int)( m        & 63u);
                const int cc2 = (int)((m >> 6 ) & 63u);
                const int cc3 = (int)((m >> 12) & 63u);
                n0 += F5_CHUNK - cc1 - cc2 - cc3;
                n1 += cc1; n2 += cc2; n3 += cc3;
                const int last = (int)((m >> 18) & 3u);
                const int rn   = (int)((m >> 20) & 63u);
                g_run  = (rn == F5_CHUNK && last == g_last) ? g_run + F5_CHUNK : rn;
                g_last = last;
            }
        }
    }
    __syncthreads();

    // ---------------- phase 3: (replay +) emit ----------------
    if (k < 63) {
        const float* ps = pshare + bi * 10;
        const float bt2    = ps[0];
        const float ol     = ps[1];
        const float la4    = ps[2];
        const float prior  = ps[3];
        const float perv   = ps[4];
        const float sw     = ps[5];
        const float ab1    = ps[6];
        const float ab2    = ps[7];
        const float beta_p = ps[8];

        float q0,q1,q2,q3, ft;
        float f0,f1,f2,f3;
        int   old_c;
        float er;

        if (k == 0) {
            q0=q1=q2=q3=prior; f0=f1=f2=f3=0.f; ft=0.f; old_c=-1;
            er = alpha_er;
        } else {
            const int row = (k <= F5_NMST) ? (k-1) : (F5_NMST-1);
            const float4 sA = smap0[row*16 + bi];
            const float4 sB = smap1[row*16 + bi];
            q0=sA.x; q1=sA.y; q2=sA.z; q3=sA.w;
            const int u1 = __float_as_int(sB.y);
            const int u2 = __float_as_int(sB.z);
            const int u3 = __float_as_int(sB.w);
            f0 = (float)(u1 & 0xFFFF); f1 = (float)(u1 >> 16);
            f2 = (float)(u2 & 0xFFFF); f3 = (float)(u2 >> 16);
            ft = (float)(u3 & 0xFFFF);
            old_c = u3 >> 16;
            const int t_state = (k <= F5_NMST) ? t0 : (F5_NMST * F5_CHUNK);
            er = alpha_er * exp2f((float)t_state * ER_L2D);
        }

        // replay state-only steps for slots 61/62 (from checkpoint 60)
        if (k > F5_NMST) {
            const int nrep = (k - F5_NMST) * 2;   // 2 words (k=61) or 4 (k=62)
            for (int w = 0; w < nrep; ++w) {
                uint32_t word = tailw[w*16 + bi];
                #pragma unroll
                for (int i = 0; i < 8; ++i) {
                    const int   code = (int)(word & 0xFu); word >>= 4;
                    const int   c    = code & 3;
                    const float r    = (float)((code >> 2) & 1);
                    const float target = fmaf(r, gp1, -gam);
                    const bool e0=(c==0), e1=(c==1), e2=(c==2), e3=(c==3);
                    q0 = e0 ? target : q0;
                    q1 = e1 ? target : q1;
                    q2 = e2 ? target : q2;
                    q3 = e3 ? target : q3;
                    const bool same = (c == old_c);
                    ft = same ? ft + 1.0f : 0.0f;
                    er *= ER_DECAY;
                    f0 += e0 ? 1.0f : 0.0f;
                    f1 += e1 ? 1.0f : 0.0f;
                    f2 += e2 ? 1.0f : 0.0f;
                    f3 += e3 ? 1.0f : 0.0f;
                    const float qm = 0.25f * ((q0+q1)+(q2+q3));
                    q0 = decay * fmaf(er, qm - q0, q0);
                    q1 = decay * fmaf(er, qm - q1, q1);
                    q2 = decay * fmaf(er, qm - q2, q2);
                    q3 = decay * fmaf(er, qm - q3, q3);
                    old_c = c;
                }
            }
        }

        float bpl0 = beta_p * __log2f(1.0f + f0);
        float bpl1 = beta_p * __log2f(1.0f + f1);
        float bpl2 = beta_p * __log2f(1.0f + f2);
        float bpl3 = beta_p * __log2f(1.0f + f3);

        float4* op = out4 + (size_t)t0 * B_SIZE + b;
        const int ngroups = (k == 62) ? 1 : 2;

        #pragma unroll
        for (int g = 0; g < 2; ++g) {
            if (g < ngroups) {
                uint32_t word = wr[g];
                #pragma unroll
                for (int i = 0; i < 8; ++i) {
                    const int   code = (int)(word & 0xFu); word >>= 4;
                    const int   c    = code & 3;
                    const float r    = (float)((code >> 2) & 1);

                    const float target = fmaf(r, gp1, -gam);
                    const bool e0=(c==0), e1=(c==1), e2=(c==2), e3=(c==3);
                    q0 = e0 ? target : q0;
                    q1 = e1 ? target : q1;
                    q2 = e2 ? target : q2;
                    q3 = e3 ? target : q3;

                    const bool same = (c == old_c);
                    ft = same ? ft + 1.0f : 0.0f;
                    er *= ER_DECAY;

                    const float fsel = e0 ? f0 : (e1 ? f1 : (e2 ? f2 : f3));
                    const float bplc = beta_p * __log2f(fsel + 2.0f);
                    f0 += e0 ? 1.0f : 0.0f;
                    f1 += e1 ? 1.0f : 0.0f;
                    f2 += e2 ? 1.0f : 0.0f;
                    f3 += e3 ? 1.0f : 0.0f;
                    bpl0 = e0 ? bplc : bpl0;
                    bpl1 = e1 ? bplc : bpl1;
                    bpl2 = e2 ? bplc : bpl2;
                    bpl3 = e3 ? bplc : bpl3;

                    const float qm = 0.25f * ((q0+q1)+(q2+q3));
                    q0 = decay * fmaf(er, qm - q0, q0);
                    q1 = decay * fmaf(er, qm - q1, q1);
                    q2 = decay * fmaf(er, qm - q2, q2);
                    q3 = decay * fmaf(er, qm - q3, q3);

                    const float s0 = fmaf(bt2, q0, bpl0);
                    const float s1 = fmaf(bt2, q1, bpl1);
                    const float s2 = fmaf(bt2, q2, bpl2);
                    const float s3 = fmaf(bt2, q3, bpl3);

                    const float m  = fmaxf(fmaxf(s0, s1), fmaxf(s2, s3));
                    const float x0 = exp2f(s0 - m);
                    const float x1 = exp2f(s1 - m);
                    const float x2 = exp2f(s2 - m);
                    const float x3 = exp2f(s3 - m);
                    const float inv = __builtin_amdgcn_rcpf((x0+x1)+(x2+x3));
                    const float sc  = ol * inv;

                    const float L0 = __log2f(fmaf(sc, x0, la4));
                    const float L1 = __log2f(fmaf(sc, x1, la4));
                    const float L2 = __log2f(fmaf(sc, x2, la4));
                    const float L3 = __log2f(fmaf(sc, x3, la4));

                    const float bonus = fmaf(LN2_F, __log2f(ft + 1.0f), same ? perv : sw);

                    float a0 = (e0 ? bonus : 0.0f) + ((old_c == 0) ? ab1 : 0.0f);
                    float a1 = (e1 ? bonus : 0.0f) + ((old_c == 1) ? ab1 : 0.0f);
                    float a2 = (e2 ? bonus : 0.0f) + ((old_c == 2) ? ab1 : 0.0f);
                    float a3 = (e3 ? bonus : 0.0f) + ((old_c == 3) ? ab1 : 0.0f);
                    const int c2 = (c + 2) & 3;
                    a0 += (c2 == 0) ? ab2 : 0.0f;
                    a1 += (c2 == 1) ? ab2 : 0.0f;
                    a2 += (c2 == 2) ? ab2 : 0.0f;
                    a3 += (c2 == 3) ? ab2 : 0.0f;

                    f32x4_t v = { fmaf(LN2_F, L0, a0), fmaf(LN2_F, L1, a1),
                                  fmaf(LN2_F, L2, a2), fmaf(LN2_F, L3, a3) };
                    __builtin_nontemporal_store(v,
                        reinterpret_cast<f32x4_t*>(op + (size_t)(g*8 + i) * B_SIZE));
                    old_c = c;
                }
            }
        }
    }
}

// ===========================================================================
// fused4 fallback — R14 kernel verbatim (proven 62.3 us).
// ===========================================================================
#define CHUNK    32
#define KCH      32
#define NM       31
#define BPB      16
#define BP       17

__global__ __launch_bounds__(512)
void castro_fused4(const float* __restrict__ params,
                   const float* __restrict__ rewards,
                   const int*   __restrict__ choices,
                   const int*   __restrict__ pids,
                   float4*      __restrict__ out4)
{
    __shared__ float4   smap0[NM][BP];
    __shared__ float4   smap1[NM][BP];
    __shared__ float4   smap2[NM][BP];
    __shared__ float4   smap3[NM][BP];
    __shared__ float4   smap4[NM][BP];
    __shared__ uint32_t smeta[NM][BP];
    __shared__ float    pshare[BPB][10];

    const int tid = threadIdx.x;
    const int k   = tid >> 4;
    const int bi  = tid & 15;
    const int b   = blockIdx.x * BPB + bi;
    const int t0  = k * CHUNK;
    const int pid = pids[b];

    const float p3  = clampf(params[ 3 * P_SIZE + pid], -5.0f, 5.0f);
    const float p4  = clampf(params[ 4 * P_SIZE + pid], -5.0f, 5.0f);
    const float p10 = clampf(params[10 * P_SIZE + pid], -5.0f, 5.0f);
    const float alpha_er = clampf(sg_(p3), 0.01f, 0.99f);
    const float decay    = clampf(sg_(p4), 0.01f, 0.99f);
    const float gam      = sp_(p10);
    const float gp1      = 1.0f + gam;

    if (tid < BPB) {
        const float q0_ = clampf(params[ 0 * P_SIZE + pid], -5.0f, 5.0f);
        const float q1_ = clampf(params[ 1 * P_SIZE + pid], -5.0f, 5.0f);
        const float q2_ = clampf(params[ 2 * P_SIZE + pid], -5.0f, 5.0f);
        const float q5_ = clampf(params[ 5 * P_SIZE + pid], -5.0f, 5.0f);
        const float q6_ = clampf(params[ 6 * P_SIZE + pid], -5.0f, 5.0f);
        const float q7_ = clampf(params[ 7 * P_SIZE + pid], -5.0f, 5.0f);
        const float q8_ = clampf(params[ 8 * P_SIZE + pid], -5.0f, 5.0f);
        const float q11 = clampf(params[11 * P_SIZE + pid], -5.0f, 5.0f);
        const float q12 = clampf(params[12 * P_SIZE + pid], -5.0f, 5.0f);
        const float beta_r = clampf(sp_(q0_), 0.01f, 20.0f);
        const float lapse  = clampf(sg_(q1_), 0.01f, 0.99f);
        const float prior  = clampf(sp_(q2_), 0.01f, 0.99f);
        const float temp   = clampf(sp_(q11) + 1e-6f, 1e-6f, 100.0f);
        pshare[tid][0] = (beta_r / temp) * LOG2E_F;
        pshare[tid][1] = 1.0f - lapse;
        pshare[tid][2] = 0.25f * lapse;
        pshare[tid][3] = prior;
        pshare[tid][4] = sp_(q7_);
        pshare[tid][5] = q8_;
        pshare[tid][6] = q5_;
        pshare[tid][7] = q6_;
        pshare[tid][8] = sp_(q12);
        pshare[tid][9] = 0.0f;
    }

    const int*   cp = choices + (size_t)t0 * B_SIZE + b;
    const float* rp = rewards + (size_t)t0 * B_SIZE + b;

    uint32_t wr[4] = {0u, 0u, 0u, 0u};

    if (k < NM) {
        float er = alpha_er * exp2f((float)t0 * ER_L2D);

        float m00=1.f,m01=0.f,m02=0.f,m03=0.f;
        float m10=0.f,m11=1.f,m12=0.f,m13=0.f;
        float m20=0.f,m21=0.f,m22=1.f,m23=0.f;
        float m30=0.f,m31=0.f,m32=0.f,m33=1.f;
        float b0=0.f,b1=0.f,b2=0.f,b3=0.f;
        int   c1=0,c2=0,c3=0;
        int   run=0, last=-1;

        int cbuf[8]; float rbuf[8];
        #pragma unroll
        for (int i = 0; i < 8; ++i) {
            cbuf[i] = cp[(size_t)i * B_SIZE];
            rbuf[i] = rp[(size_t)i * B_SIZE];
        }

        #pragma unroll
        for (int g = 0; g < 4; ++g) {
            int cc[8]; float rr[8];
            #pragma unroll
            for (int i = 0; i < 8; ++i) { cc[i]=cbuf[i]; rr[i]=rbuf[i]; }
            if (g < 3) {
                #pragma unroll
                for (int i = 0; i < 8; ++i) {
                    cbuf[i] = cp[(size_t)((g+1)*8 + i) * B_SIZE];
                    rbuf[i] = rp[(size_t)((g+1)*8 + i) * B_SIZE];
                }
            }
            uint32_t gw = 0;
            #pragma unroll
            for (int i = 0; i < 8; ++i) {
                const int   c = cc[i];
                const float r = rr[i];
                gw |= ((uint32_t)c | (r > 0.5f ? 4u : 0u)) << (4*i);

                er *= ER_DECAY;
                const float target = fmaf(r, gp1, -gam);
                const bool e0=(c==0), e1=(c==1), e2=(c==2), e3=(c==3);

                m00=e0?0.f:m00; m01=e0?0.f:m01; m02=e0?0.f:m02; m03=e0?0.f:m03; b0=e0?target:b0;
                m10=e1?0.f:m10; m11=e1?0.f:m11; m12=e1?0.f:m12; m13=e1?0.f:m13; b1=e1?target:b1;
                m20=e2?0.f:m20; m21=e2?0.f:m21; m22=e2?0.f:m22; m23=e2?0.f:m23; b2=e2?target:b2;
                m30=e3?0.f:m30; m31=e3?0.f:m31; m32=e3?0.f:m32; m33=e3?0.f:m33; b3=e3?target:b3;

                const float s0=(m00+m10)+(m20+m30);
                const float s1=(m01+m11)+(m21+m31);
                const float s2=(m02+m12)+(m22+m32);
                const float s3=(m03+m13)+(m23+m33);
                const float sb=(b0+b1)+(b2+b3);
                const float a  = decay * (1.0f - er);
                const float e4 = decay * er * 0.25f;

                m00=fmaf(e4,s0,a*m00); m01=fmaf(e4,s1,a*m01); m02=fmaf(e4,s2,a*m02); m03=fmaf(e4,s3,a*m03);
                m10=fmaf(e4,s0,a*m10); m11=fmaf(e4,s1,a*m11); m12=fmaf(e4,s2,a*m12); m13=fmaf(e4,s3,a*m13);
                m20=fmaf(e4,s0,a*m20); m21=fmaf(e4,s1,a*m21); m22=fmaf(e4,s2,a*m22); m23=fmaf(e4,s3,a*m23);
                m30=fmaf(e4,s0,a*m30); m31=fmaf(e4,s1,a*m31); m32=fmaf(e4,s2,a*m32); m33=fmaf(e4,s3,a*m33);
                b0=fmaf(e4,sb,a*b0); b1=fmaf(e4,sb,a*b1); b2=fmaf(e4,sb,a*b2); b3=fmaf(e4,sb,a*b3);

                c1 += e1; c2 += e2; c3 += e3;
                run = (c == last) ? run + 1 : 1;
                last = c;
            }
            wr[g] = gw;
        }

        smap0[k][bi] = make_float4(m00,m01,m02,m03);
        smap1[k][bi] = make_float4(m10,m11,m12,m13);
        smap2[k][bi] = make_float4(m20,m21,m22,m23);
        smap3[k][bi] = make_float4(m30,m31,m32,m33);
        smap4[k][bi] = make_float4(b0,b1,b2,b3);
        smeta[k][bi] = (uint32_t)c1 | ((uint32_t)c2<<6) | ((uint32_t)c3<<12)
                     | ((uint32_t)last<<18) | ((uint32_t)run<<20);
    } else {
        uint32_t gw = 0;
        #pragma unroll
        for (int i = 0; i < 8; ++i) {
            const int   c = cp[(size_t)i * B_SIZE];
            const float r = rp[(size_t)i * B_SIZE];
            gw |= ((uint32_t)c | (r > 0.5f ? 4u : 0u)) << (4*i);
        }
        wr[0] = gw;
    }

    __syncthreads();

    if (tid < BPB) {
        const float prior = pshare[tid][3];
        float q0=prior, q1=prior, q2=prior, q3=prior;
        int n0=0,n1=0,n2=0,n3=0;
        int g_run=0, g_last=-1;

        for (int k2 = 0; k2 < KCH; ++k2) {
            if (k2 > 0) {
                const int tsls = g_run - 1;
                smap0[k2-1][tid] = make_float4(q0,q1,q2,q3);
                smap1[k2-1][tid] = make_float4(0.0f,
                                               __int_as_float(n0 | (n1<<16)),
                                               __int_as_float(n2 | (n3<<16)),
                                               __int_as_float((tsls & 0xFFFF) | (g_last<<16)));
            }
            if (k2 < NM) {
                const float4 r0 = smap0[k2][tid];
                const float4 r1 = smap1[k2][tid];
                const float4 r2 = smap2[k2][tid];
                const float4 r3 = smap3[k2][tid];
                const float4 r4 = smap4[k2][tid];
                const uint32_t m = smeta[k2][tid];
                const float nq0 = fmaf(r0.w,q3, fmaf(r0.z,q2, fmaf(r0.y,q1, fmaf(r0.x,q0, r4.x))));
                const float nq1 = fmaf(r1.w,q3, fmaf(r1.z,q2, fmaf(r1.y,q1, fmaf(r1.x,q0, r4.y))));
                const float nq2 = fmaf(r2.w,q3, fmaf(r2.z,q2, fmaf(r2.y,q1, fmaf(r2.x,q0, r4.z))));
                const float nq3 = fmaf(r3.w,q3, fmaf(r3.z,q2, fmaf(r3.y,q1, fmaf(r3.x,q0, r4.w))));
                q0=nq0; q1=nq1; q2=nq2; q3=nq3;

                const int cc1 = (int)( m        & 63u);
                const int cc2 = (int)((m >> 6 ) & 63u);
                const int cc3 = (int)((m >> 12) & 63u);
                n0 += CHUNK - cc1 - cc2 - cc3;
                n1 += cc1; n2 += cc2; n3 += cc3;
                const int last = (int)((m >> 18) & 3u);
                const int rn   = (int)((m >> 20) & 63u);
                g_run  = (rn == CHUNK && last == g_last) ? g_run + CHUNK : rn;
                g_last = last;
            }
        }
    }
    __syncthreads();

    {
        const float bt2    = pshare[bi][0];
        const float ol     = pshare[bi][1];
        const float la4    = pshare[bi][2];
        const float prior  = pshare[bi][3];
        const float perv   = pshare[bi][4];
        const float sw     = pshare[bi][5];
        const float ab1    = pshare[bi][6];
        const float ab2    = pshare[bi][7];
        const float beta_p = pshare[bi][8];

        float q0,q1,q2,q3, ft;
        float f0,f1,f2,f3;
        int   old_c;
        if (k == 0) {
            q0=q1=q2=q3=prior; f0=f1=f2=f3=0.f; ft=0.f; old_c=-1;
        } else {
            const float4 sA = smap0[k-1][bi];
            const float4 sB = smap1[k-1][bi];
            q0=sA.x; q1=sA.y; q2=sA.z; q3=sA.w;
            const int u1 = __float_as_int(sB.y);
            const int u2 = __float_as_int(sB.z);
            const int u3 = __float_as_int(sB.w);
            f0 = (float)(u1 & 0xFFFF); f1 = (float)(u1 >> 16);
            f2 = (float)(u2 & 0xFFFF); f3 = (float)(u2 >> 16);
            ft = (float)(u3 & 0xFFFF);
            old_c = u3 >> 16;
        }
        float er = alpha_er * exp2f((float)t0 * ER_L2D);

        float bpl0 = beta_p * __log2f(1.0f + f0);
        float bpl1 = beta_p * __log2f(1.0f + f1);
        float bpl2 = beta_p * __log2f(1.0f + f2);
        float bpl3 = beta_p * __log2f(1.0f + f3);

        float4* op = out4 + (size_t)t0 * B_SIZE + b;
        const int ngroups = (k == NM) ? 1 : 4;

        #pragma unroll
        for (int g = 0; g < 4; ++g) {
            if (g < ngroups) {
                uint32_t word = wr[g];
                #pragma unroll
                for (int i = 0; i < 8; ++i) {
                    const int   code = (int)(word & 0xFu); word >>= 4;
                    const int   c    = code & 3;
                    const float r    = (float)((code >> 2) & 1);

                    const float target = fmaf(r, gp1, -gam);
                    const bool e0=(c==0), e1=(c==1), e2=(c==2), e3=(c==3);
                    q0 = e0 ? target : q0;
                    q1 = e1 ? target : q1;
                    q2 = e2 ? target : q2;
                    q3 = e3 ? target : q3;

                    const bool same = (c == old_c);
                    ft = same ? ft + 1.0f : 0.0f;
                    er *= ER_DECAY;

                    const float fsel = e0 ? f0 : (e1 ? f1 : (e2 ? f2 : f3));
                    const float bplc = beta_p * __log2f(fsel + 2.0f);
                    f0 += e0 ? 1.0f : 0.0f;
                    f1 += e1 ? 1.0f : 0.0f;
                    f2 += e2 ? 1.0f : 0.0f;
                    f3 += e3 ? 1.0f : 0.0f;
                    bpl0 = e0 ? bplc : bpl0;
                    bpl1 = e1 ? bplc : bpl1;
                    bpl2 = e2 ? bplc : bpl2;
                    bpl3 = e3 ? bplc : bpl3;

                    const float qm = 0.25f * ((q0+q1)+(q2+q3));
                    q0 = decay * fmaf(er, qm - q0, q0);
                    q1 = decay * fmaf(er, qm - q1, q1);
                    q2 = decay * fmaf(er, qm - q2, q2);
                    q3 = decay * fmaf(er, qm - q3, q3);

                    const float s0 = fmaf(bt2, q0, bpl0);
                    const float s1 = fmaf(bt2, q1, bpl1);
                    const float s2 = fmaf(bt2, q2, bpl2);
                    const float s3 = fmaf(bt2, q3, bpl3);

                    const float m  = fmaxf(fmaxf(s0, s1), fmaxf(s2, s3));
                    const float x0 = exp2f(s0 - m);
                    const float x1 = exp2f(s1 - m);
                    const float x2 = exp2f(s2 - m);
                    const float x3 = exp2f(s3 - m);
                    const float inv = __builtin_amdgcn_rcpf((x0+x1)+(x2+x3));
                    const float sc  = ol * inv;

                    const float L0 = __log2f(fmaf(sc, x0, la4));
                    const float L1 = __log2f(fmaf(sc, x1, la4));
                    const float L2 = __log2f(fmaf(sc, x2, la4));
                    const float L3 = __log2f(fmaf(sc, x3, la4));

                    const float bonus = fmaf(LN2_F, __log2f(ft + 1.0f), same ? perv : sw);

                    float a0 = (e0 ? bonus : 0.0f) + ((old_c == 0) ? ab1 : 0.0f);
                    float a1 = (e1 ? bonus : 0.0f) + ((old_c == 1) ? ab1 : 0.0f);
                    float a2 = (e2 ? bonus : 0.0f) + ((old_c == 2) ? ab1 : 0.0f);
                    float a3 = (e3 ? bonus : 0.0f) + ((old_c == 3) ? ab1 : 0.0f);
                    const int c2 = (c + 2) & 3;
                    a0 += (c2 == 0) ? ab2 : 0.0f;
                    a1 += (c2 == 1) ? ab2 : 0.0f;
                    a2 += (c2 == 2) ? ab2 : 0.0f;
                    a3 += (c2 == 3) ? ab2 : 0.0f;

                    f32x4_t v = { fmaf(LN2_F, L0, a0), fmaf(LN2_F, L1, a1),
                                  fmaf(LN2_F, L2, a2), fmaf(LN2_F, L3, a3) };
                    __builtin_nontemporal_store(v,
                        reinterpret_cast<f32x4_t*>(op + (size_t)(g*8 + i) * B_SIZE));
                    old_c = c;
                }
            }
        }
    }
}

extern "C" void kernel_launch(void* const* d_in, const int* in_sizes, int n_in,
                              void* d_out, int out_size, void* d_ws, size_t ws_size,
                              hipStream_t stream)
{
    const float* params  = (const float*)d_in[0];
    const float* rewards = (const float*)d_in[1];
    const int*   choices = (const int*)  d_in[2];
    const int*   pids    = (const int*)  d_in[3];

    hipError_t e = hipFuncSetAttribute(
        reinterpret_cast<const void*>(castro_fused5),
        hipFuncAttributeMaxDynamicSharedMemorySize, F5_LDS_BYTES);

    if (e == hipSuccess) {
        hipLaunchKernelGGL(castro_fused5, dim3(B_SIZE/16), dim3(1024),
                           F5_LDS_BYTES, stream,
                           params, rewards, choices, pids, (float4*)d_out);
    } else {
        hipLaunchKernelGGL(castro_fused4, dim3(B_SIZE/16), dim3(512), 0, stream,
                           params, rewards, choices, pids, (float4*)d_out);
    }
}

// Round 16
// 66.477 us; speedup vs baseline: 1.2160x; 1.2160x over previous
//
#include <hip/hip_runtime.h>
#include <stdint.h>

#define T_TRIALS 1000
#define B_SIZE   8192
#define P_SIZE   1024
#define CHUNK    32
#define KCH      32            // 31 full chunks + 8-step tail
#define NM       31            // maps 0..30 feed the scan
#define BPB      16            // batch elements per block (>=16: 64B segments)
#define BP       17            // padded row
#define ER_DECAY 0.999f
#define ER_L2D   (-1.4434228e-3f)   // log2(0.999)
#define LOG2E_F 1.4426950408889634f
#define LN2_F   0.69314718055994531f

typedef float f32x4_t __attribute__((ext_vector_type(4)));
typedef float f32x2_t __attribute__((ext_vector_type(2)));

__device__ __forceinline__ float sp_(float x){ return __logf(1.0f + __expf(x)); }   // softplus
__device__ __forceinline__ float sg_(float x){ return 1.0f / (1.0f + __expf(-x)); } // sigmoid
__device__ __forceinline__ float clampf(float x, float lo, float hi){ return fminf(fmaxf(x, lo), hi); }
__device__ __forceinline__ f32x2_t pkfma(f32x2_t a, f32x2_t b, f32x2_t c){ return __builtin_elementwise_fma(a, b, c); }

// ===========================================================================
// fused6 = fused4 + packed fp32 + LDS log2 table + select-target.
// Block = 512 threads = 32 chunks (k = tid>>4) x 16 b (bi = tid&15).
// ===========================================================================
__global__ __launch_bounds__(512)
void castro_fused6(const float* __restrict__ params,
                   const float* __restrict__ rewards,
                   const int*   __restrict__ choices,
                   const int*   __restrict__ pids,
                   float4*      __restrict__ out4)
{
    __shared__ float4   smap0[NM][BP];
    __shared__ float4   smap1[NM][BP];
    __shared__ float4   smap2[NM][BP];
    __shared__ float4   smap3[NM][BP];
    __shared__ float4   smap4[NM][BP];
    __shared__ uint32_t smeta[NM][BP];
    __shared__ float    pshare[BPB][10];
    __shared__ float    ltab[1024];          // ltab[i] = log2(i), i>=1

    const int tid = threadIdx.x;
    const int k   = tid >> 4;
    const int bi  = tid & 15;
    const int b   = blockIdx.x * BPB + bi;
    const int t0  = k * CHUNK;
    const int pid = pids[b];

    // log2 table (done before first barrier)
    #pragma unroll
    for (int i = tid; i < 1024; i += 512)
        ltab[i] = __log2f((float)(i < 1 ? 1 : i));

    // phase-1 params
    const float p3  = clampf(params[ 3 * P_SIZE + pid], -5.0f, 5.0f);
    const float p4  = clampf(params[ 4 * P_SIZE + pid], -5.0f, 5.0f);
    const float p10 = clampf(params[10 * P_SIZE + pid], -5.0f, 5.0f);
    const float alpha_er = clampf(sg_(p3), 0.01f, 0.99f);
    const float decay    = clampf(sg_(p4), 0.01f, 0.99f);
    const float gam      = sp_(p10);
    const float ngam     = -gam;

    if (tid < BPB) {
        const float q0_ = clampf(params[ 0 * P_SIZE + pid], -5.0f, 5.0f);
        const float q1_ = clampf(params[ 1 * P_SIZE + pid], -5.0f, 5.0f);
        const float q2_ = clampf(params[ 2 * P_SIZE + pid], -5.0f, 5.0f);
        const float q5_ = clampf(params[ 5 * P_SIZE + pid], -5.0f, 5.0f);
        const float q6_ = clampf(params[ 6 * P_SIZE + pid], -5.0f, 5.0f);
        const float q7_ = clampf(params[ 7 * P_SIZE + pid], -5.0f, 5.0f);
        const float q8_ = clampf(params[ 8 * P_SIZE + pid], -5.0f, 5.0f);
        const float q11 = clampf(params[11 * P_SIZE + pid], -5.0f, 5.0f);
        const float q12 = clampf(params[12 * P_SIZE + pid], -5.0f, 5.0f);
        const float beta_r = clampf(sp_(q0_), 0.01f, 20.0f);
        const float lapse  = clampf(sg_(q1_), 0.01f, 0.99f);
        const float prior  = clampf(sp_(q2_), 0.01f, 0.99f);
        const float temp   = clampf(sp_(q11) + 1e-6f, 1e-6f, 100.0f);
        pshare[tid][0] = (beta_r / temp) * LOG2E_F;
        pshare[tid][1] = 1.0f - lapse;
        pshare[tid][2] = 0.25f * lapse;
        pshare[tid][3] = prior;
        pshare[tid][4] = sp_(q7_);
        pshare[tid][5] = q8_;
        pshare[tid][6] = q5_;
        pshare[tid][7] = q6_;
        pshare[tid][8] = sp_(q12);
        pshare[tid][9] = 0.0f;
    }

    const int*   cp = choices + (size_t)t0 * B_SIZE + b;
    const float* rp = rewards + (size_t)t0 * B_SIZE + b;

    uint32_t wr[4] = {0u, 0u, 0u, 0u};

    // ---------------- phase 1: pack + per-chunk map composition (packed) ------
    if (k < NM) {
        float er = alpha_er * exp2f((float)t0 * ER_L2D);

        // row i of M as two packed halves {m_i0,m_i1},{m_i2,m_i3}
        f32x2_t r0l = {1.f,0.f}, r0h = {0.f,0.f};
        f32x2_t r1l = {0.f,1.f}, r1h = {0.f,0.f};
        f32x2_t r2l = {0.f,0.f}, r2h = {1.f,0.f};
        f32x2_t r3l = {0.f,0.f}, r3h = {0.f,1.f};
        f32x2_t b01 = {0.f,0.f}, b23 = {0.f,0.f};
        const f32x2_t zz = {0.f,0.f};
        int   c1=0,c2=0,c3=0;
        int   run=0, last=-1;

        int cbuf[8]; float rbuf[8];
        #pragma unroll
        for (int i = 0; i < 8; ++i) {
            cbuf[i] = cp[(size_t)i * B_SIZE];
            rbuf[i] = rp[(size_t)i * B_SIZE];
        }

        #pragma unroll
        for (int g = 0; g < 4; ++g) {
            int cc[8]; float rr[8];
            #pragma unroll
            for (int i = 0; i < 8; ++i) { cc[i]=cbuf[i]; rr[i]=rbuf[i]; }
            if (g < 3) {
                #pragma unroll
                for (int i = 0; i < 8; ++i) {
                    cbuf[i] = cp[(size_t)((g+1)*8 + i) * B_SIZE];
                    rbuf[i] = rp[(size_t)((g+1)*8 + i) * B_SIZE];
                }
            }
            uint32_t gw = 0;
            #pragma unroll
            for (int i = 0; i < 8; ++i) {
                const int  c    = cc[i];
                const bool rbit = (rr[i] > 0.5f);
                gw |= ((uint32_t)c | (rbit ? 4u : 0u)) << (4*i);

                er *= ER_DECAY;
                const float target = rbit ? 1.0f : ngam;
                const bool e0=(c==0), e1=(c==1), e2=(c==2), e3=(c==3);

                r0l = e0 ? zz : r0l;  r0h = e0 ? zz : r0h;  b01.x = e0 ? target : b01.x;
                r1l = e1 ? zz : r1l;  r1h = e1 ? zz : r1h;  b01.y = e1 ? target : b01.y;
                r2l = e2 ? zz : r2l;  r2h = e2 ? zz : r2h;  b23.x = e2 ? target : b23.x;
                r3l = e3 ? zz : r3l;  r3h = e3 ? zz : r3h;  b23.y = e3 ? target : b23.y;

                const f32x2_t sl = (r0l + r1l) + (r2l + r3l);   // col sums 0,1
                const f32x2_t sh = (r0h + r1h) + (r2h + r3h);   // col sums 2,3
                const f32x2_t sbv = b01 + b23;
                const float   sb  = sbv.x + sbv.y;
                const float a  = decay * (1.0f - er);
                const float e4 = decay * er * 0.25f;
                const f32x2_t av  = {a, a};
                const f32x2_t e4v = {e4, e4};
                const f32x2_t sbp = {sb, sb};

                r0l = pkfma(e4v, sl, r0l*av);  r0h = pkfma(e4v, sh, r0h*av);
                r1l = pkfma(e4v, sl, r1l*av);  r1h = pkfma(e4v, sh, r1h*av);
                r2l = pkfma(e4v, sl, r2l*av);  r2h = pkfma(e4v, sh, r2h*av);
                r3l = pkfma(e4v, sl, r3l*av);  r3h = pkfma(e4v, sh, r3h*av);
                b01 = pkfma(e4v, sbp, b01*av); b23 = pkfma(e4v, sbp, b23*av);

                c1 += e1; c2 += e2; c3 += e3;
                run = (c == last) ? run + 1 : 1;
                last = c;
            }
            wr[g] = gw;
        }

        smap0[k][bi] = make_float4(r0l.x, r0l.y, r0h.x, r0h.y);
        smap1[k][bi] = make_float4(r1l.x, r1l.y, r1h.x, r1h.y);
        smap2[k][bi] = make_float4(r2l.x, r2l.y, r2h.x, r2h.y);
        smap3[k][bi] = make_float4(r3l.x, r3l.y, r3h.x, r3h.y);
        smap4[k][bi] = make_float4(b01.x, b01.y, b23.x, b23.y);
        smeta[k][bi] = (uint32_t)c1 | ((uint32_t)c2<<6) | ((uint32_t)c3<<12)
                     | ((uint32_t)last<<18) | ((uint32_t)run<<20);
    } else {
        // tail chunk [992,1000): pack only
        uint32_t gw = 0;
        #pragma unroll
        for (int i = 0; i < 8; ++i) {
            const int   c = cp[(size_t)i * B_SIZE];
            const float r = rp[(size_t)i * B_SIZE];
            gw |= ((uint32_t)c | (r > 0.5f ? 4u : 0u)) << (4*i);
        }
        wr[0] = gw;
    }

    __syncthreads();

    // ---------------- phase 2: serial scan (threads 0..15, one per b) ----------
    if (tid < BPB) {
        const float prior = pshare[tid][3];
        float q0=prior, q1=prior, q2=prior, q3=prior;
        int n0=0,n1=0,n2=0,n3=0;
        int g_run=0, g_last=-1;

        for (int k2 = 0; k2 < KCH; ++k2) {
            if (k2 > 0) {
                const int tsls = g_run - 1;
                smap0[k2-1][tid] = make_float4(q0,q1,q2,q3);
                smap1[k2-1][tid] = make_float4(0.0f,
                                               __int_as_float(n0 | (n1<<16)),
                                               __int_as_float(n2 | (n3<<16)),
                                               __int_as_float((tsls & 0xFFFF) | (g_last<<16)));
            }
            if (k2 < NM) {
                const float4 r0 = smap0[k2][tid];
                const float4 r1 = smap1[k2][tid];
                const float4 r2 = smap2[k2][tid];
                const float4 r3 = smap3[k2][tid];
                const float4 r4 = smap4[k2][tid];
                const uint32_t m = smeta[k2][tid];
                const float nq0 = fmaf(r0.w,q3, fmaf(r0.z,q2, fmaf(r0.y,q1, fmaf(r0.x,q0, r4.x))));
                const float nq1 = fmaf(r1.w,q3, fmaf(r1.z,q2, fmaf(r1.y,q1, fmaf(r1.x,q0, r4.y))));
                const float nq2 = fmaf(r2.w,q3, fmaf(r2.z,q2, fmaf(r2.y,q1, fmaf(r2.x,q0, r4.z))));
                const float nq3 = fmaf(r3.w,q3, fmaf(r3.z,q2, fmaf(r3.y,q1, fmaf(r3.x,q0, r4.w))));
                q0=nq0; q1=nq1; q2=nq2; q3=nq3;

                const int cc1 = (int)( m        & 63u);
                const int cc2 = (int)((m >> 6 ) & 63u);
                const int cc3 = (int)((m >> 12) & 63u);
                n0 += CHUNK - cc1 - cc2 - cc3;
                n1 += cc1; n2 += cc2; n3 += cc3;
                const int last = (int)((m >> 18) & 3u);
                const int rn   = (int)((m >> 20) & 63u);
                g_run  = (rn == CHUNK && last == g_last) ? g_run + CHUNK : rn;
                g_last = last;
            }
        }
    }
    __syncthreads();

    // ---------------- phase 3: emit logits (packed + table) --------------------
    {
        const float bt2    = pshare[bi][0];
        const float ol     = pshare[bi][1];
        const float la4    = pshare[bi][2];
        const float prior  = pshare[bi][3];
        const float perv   = pshare[bi][4];
        const float sw     = pshare[bi][5];
        const float ab1    = pshare[bi][6];
        const float ab2    = pshare[bi][7];
        const float beta_p = pshare[bi][8];

        f32x2_t q01, q23;
        int   n0,n1,n2,n3, ft_i, old_c;
        if (k == 0) {
            q01 = (f32x2_t){prior, prior}; q23 = q01;
            n0=n1=n2=n3=0; ft_i=0; old_c=-1;
        } else {
            const float4 sA = smap0[k-1][bi];
            const float4 sB = smap1[k-1][bi];
            q01 = (f32x2_t){sA.x, sA.y}; q23 = (f32x2_t){sA.z, sA.w};
            const int u1 = __float_as_int(sB.y);
            const int u2 = __float_as_int(sB.z);
            const int u3 = __float_as_int(sB.w);
            n0 = u1 & 0xFFFF; n1 = u1 >> 16;
            n2 = u2 & 0xFFFF; n3 = u2 >> 16;
            ft_i = u3 & 0xFFFF;
            old_c = u3 >> 16;
        }
        float er = alpha_er * exp2f((float)t0 * ER_L2D);

        f32x2_t bpl01 = { beta_p * ltab[n0 + 1], beta_p * ltab[n1 + 1] };
        f32x2_t bpl23 = { beta_p * ltab[n2 + 1], beta_p * ltab[n3 + 1] };

        const f32x2_t bt2v = {bt2, bt2};
        const f32x2_t la4v = {la4, la4};
        const f32x2_t ln2v = {LN2_F, LN2_F};

        float4* op = out4 + (size_t)t0 * B_SIZE + b;
        const int ngroups = (k == NM) ? 1 : 4;

        #pragma unroll
        for (int g = 0; g < 4; ++g) {
            if (g < ngroups) {
                uint32_t word = wr[g];
                #pragma unroll
                for (int i = 0; i < 8; ++i) {
                    const int code = (int)(word & 0xFu); word >>= 4;
                    const int c    = code & 3;
                    const float target = (code & 4) ? 1.0f : ngam;
                    const bool e0=(c==0), e1=(c==1), e2=(c==2), e3=(c==3);

                    q01.x = e0 ? target : q01.x;
                    q01.y = e1 ? target : q01.y;
                    q23.x = e2 ? target : q23.x;
                    q23.y = e3 ? target : q23.y;

                    const bool same = (c == old_c);
                    ft_i = same ? ft_i + 1 : 0;
                    er *= ER_DECAY;

                    const int nsel = e0 ? n0 : (e1 ? n1 : (e2 ? n2 : n3));
                    const float bplc = beta_p * ltab[nsel + 2];
                    n0 += e0; n1 += e1; n2 += e2; n3 += e3;
                    bpl01.x = e0 ? bplc : bpl01.x;
                    bpl01.y = e1 ? bplc : bpl01.y;
                    bpl23.x = e2 ? bplc : bpl23.x;
                    bpl23.y = e3 ? bplc : bpl23.y;

                    const f32x2_t qs = q01 + q23;
                    const float   qm = 0.25f * (qs.x + qs.y);
                    const f32x2_t qmv = {qm, qm};
                    const f32x2_t erv = {er, er};
                    const f32x2_t dcv = {decay, decay};
                    q01 = pkfma(erv, qmv - q01, q01) * dcv;
                    q23 = pkfma(erv, qmv - q23, q23) * dcv;

                    const f32x2_t s01 = pkfma(bt2v, q01, bpl01);
                    const f32x2_t s23 = pkfma(bt2v, q23, bpl23);

                    const float m = fmaxf(fmaxf(s01.x, s01.y), fmaxf(s23.x, s23.y));
                    const f32x2_t mv = {m, m};
                    const f32x2_t d01 = s01 - mv;
                    const f32x2_t d23 = s23 - mv;
                    const float x0 = exp2f(d01.x);
                    const float x1 = exp2f(d01.y);
                    const float x2 = exp2f(d23.x);
                    const float x3 = exp2f(d23.y);
                    const float inv = __builtin_amdgcn_rcpf((x0+x1)+(x2+x3));
                    const float sc  = ol * inv;
                    const f32x2_t scv = {sc, sc};

                    const f32x2_t y01 = pkfma(scv, (f32x2_t){x0,x1}, la4v);
                    const f32x2_t y23 = pkfma(scv, (f32x2_t){x2,x3}, la4v);
                    const float L0 = __log2f(y01.x);
                    const float L1 = __log2f(y01.y);
                    const float L2 = __log2f(y23.x);
                    const float L3 = __log2f(y23.y);

                    const float bonus = fmaf(LN2_F, ltab[ft_i + 1], same ? perv : sw);

                    float a0 = (e0 ? bonus : 0.0f) + ((old_c == 0) ? ab1 : 0.0f);
                    float a1 = (e1 ? bonus : 0.0f) + ((old_c == 1) ? ab1 : 0.0f);
                    float a2 = (e2 ? bonus : 0.0f) + ((old_c == 2) ? ab1 : 0.0f);
                    float a3 = (e3 ? bonus : 0.0f) + ((old_c == 3) ? ab1 : 0.0f);
                    const int c2 = (c + 2) & 3;
                    a0 += (c2 == 0) ? ab2 : 0.0f;
                    a1 += (c2 == 1) ? ab2 : 0.0f;
                    a2 += (c2 == 2) ? ab2 : 0.0f;
                    a3 += (c2 == 3) ? ab2 : 0.0f;

                    const f32x2_t o01 = pkfma(ln2v, (f32x2_t){L0,L1}, (f32x2_t){a0,a1});
                    const f32x2_t o23 = pkfma(ln2v, (f32x2_t){L2,L3}, (f32x2_t){a2,a3});

                    f32x4_t v = { o01.x, o01.y, o23.x, o23.y };
                    __builtin_nontemporal_store(v,
                        reinterpret_cast<f32x4_t*>(op + (size_t)(g*8 + i) * B_SIZE));
                    old_c = c;
                }
            }
        }
    }
}

extern "C" void kernel_launch(void* const* d_in, const int* in_sizes, int n_in,
                              void* d_out, int out_size, void* d_ws, size_t ws_size,
                              hipStream_t stream)
{
    const float* params  = (const float*)d_in[0];
    const float* rewards = (const float*)d_in[1];
    const int*   choices = (const int*)  d_in[2];
    const int*   pids    = (const int*)  d_in[3];

    hipLaunchKernelGGL(castro_fused6, dim3(B_SIZE/BPB), dim3(512), 0, stream,
                       params, rewards, choices, pids, (float4*)d_out);
}